// Round 1
// baseline (115.883 us; speedup 1.0000x reference)
//
#include <hip/hip_runtime.h>
#include <hip/hip_bf16.h>

typedef float f32x4 __attribute__((ext_vector_type(4)));
typedef __bf16 bf16x8 __attribute__((ext_vector_type(8)));

static __device__ __forceinline__ unsigned short f2bf(float f) {
    unsigned int u = __float_as_uint(f);
    unsigned int r = (u + 0x7fffu + ((u >> 16) & 1u)) >> 16;   // RNE
    return (unsigned short)r;
}

// ---------------- pack kernels ----------------
__global__ void pack_x(const float* __restrict__ in, unsigned short* __restrict__ out, int n4) {
    int i = blockIdx.x * blockDim.x + threadIdx.x;
    if (i >= n4) return;
    float4 v = reinterpret_cast<const float4*>(in)[i];
    ushort4 o;
    o.x = f2bf(v.x); o.y = f2bf(v.y); o.z = f2bf(v.z); o.w = f2bf(v.w);
    reinterpret_cast<ushort4*>(out)[i] = o;
}

// w: [F=256][Cin=256][K=3] f32 -> wp: [F][kk*256+cin] bf16
__global__ void pack_w(const float* __restrict__ w, unsigned short* __restrict__ wp) {
    int i = blockIdx.x * blockDim.x + threadIdx.x;
    if (i >= 256 * 256 * 3) return;
    int f = i / 768;
    int rem = i - f * 768;
    int cin = rem / 3;
    int kk = rem - cin * 3;
    wp[f * 768 + kk * 256 + cin] = f2bf(w[i]);
}

// ---------------- conv as implicit-im2col GEMM (bf16 MFMA) ----------------
// A: [B*T, 256] bf16 ; Wp: [256][768] bf16 ; out = relu(A_im2col @ Wp^T + bias), f32
#define BM 128
#define BN 128
#define BK 64

__global__ __launch_bounds__(256) void conv_gemm(
    const unsigned short* __restrict__ A,
    const unsigned short* __restrict__ Wp,
    const float* __restrict__ bias,
    float* __restrict__ out,
    int T)
{
    __shared__ __align__(16) unsigned short As[BM][72];   // +8 pad: 2-way bank alias only
    __shared__ __align__(16) unsigned short Bs[BN][72];

    const int tid = threadIdx.x;
    const int lane = tid & 63;
    const int w = tid >> 6;
    const int wm = (w >> 1) * 64, wn = (w & 1) * 64;
    const int grp = lane >> 4, lr = lane & 15;

    const int m0 = blockIdx.x * BM;
    const int n0 = blockIdx.y * BN;
    const int b = m0 / T;           // BM=128 divides T=512: tile within one batch
    const int t_base = m0 % T;

    f32x4 acc[4][4] = {};

    for (int kt = 0; kt < 768 / BK; ++kt) {
        const int k0 = kt * BK;
        const int kk = k0 >> 8;       // which of the 3 taps
        const int cin0 = k0 & 255;
        // stage: 1024 chunks of 16B each for A and B
        #pragma unroll
        for (int i = 0; i < 4; ++i) {
            int c = i * 256 + tid;
            int r = c >> 3, seg = c & 7;
            int tt = t_base + r + kk - 1;
            uint4 val = make_uint4(0u, 0u, 0u, 0u);
            if ((unsigned)tt < (unsigned)T)
                val = *reinterpret_cast<const uint4*>(A + ((size_t)(b * T + tt)) * 256 + cin0 + seg * 8);
            *reinterpret_cast<uint4*>(&As[r][seg * 8]) = val;
            *reinterpret_cast<uint4*>(&Bs[r][seg * 8]) =
                *reinterpret_cast<const uint4*>(Wp + (size_t)(n0 + r) * 768 + k0 + seg * 8);
        }
        __syncthreads();
        #pragma unroll
        for (int ks = 0; ks < 2; ++ks) {
            bf16x8 af[4], bf[4];
            #pragma unroll
            for (int i = 0; i < 4; ++i) {
                af[i] = *reinterpret_cast<const bf16x8*>(&As[wm + i * 16 + lr][ks * 32 + grp * 8]);
                bf[i] = *reinterpret_cast<const bf16x8*>(&Bs[wn + i * 16 + lr][ks * 32 + grp * 8]);
            }
            #pragma unroll
            for (int mi = 0; mi < 4; ++mi)
                #pragma unroll
                for (int ni = 0; ni < 4; ++ni)
                    acc[mi][ni] = __builtin_amdgcn_mfma_f32_16x16x32_bf16(af[mi], bf[ni], acc[mi][ni], 0, 0, 0);
        }
        __syncthreads();
    }

    // epilogue: +bias, relu, store f32. C/D: col=lane&15, row=(lane>>4)*4+reg
    #pragma unroll
    for (int ni = 0; ni < 4; ++ni) {
        int f = n0 + wn + ni * 16 + lr;
        float bv = bias[f];
        #pragma unroll
        for (int mi = 0; mi < 4; ++mi) {
            int mrow = m0 + wm + mi * 16 + grp * 4;
            #pragma unroll
            for (int r = 0; r < 4; ++r) {
                float v = acc[mi][ni][r] + bv;
                out[(size_t)(mrow + r) * 256 + f] = fmaxf(v, 0.f);
            }
        }
    }
}

// ---------------- LayerNorm (wave per row) -> bf16 out ----------------
__global__ void ln_bf16(const float* __restrict__ in, const float* __restrict__ g,
                        const float* __restrict__ be, unsigned short* __restrict__ out) {
    int lane = threadIdx.x & 63;
    int wv = threadIdx.x >> 6;
    int row = blockIdx.x * 4 + wv;
    const float* p = in + (size_t)row * 256;
    float4 v = reinterpret_cast<const float4*>(p)[lane];
    float s = v.x + v.y + v.z + v.w;
    float sq = v.x * v.x + v.y * v.y + v.z * v.z + v.w * v.w;
    #pragma unroll
    for (int off = 32; off; off >>= 1) {
        s += __shfl_xor(s, off);
        sq += __shfl_xor(sq, off);
    }
    float mu = s * (1.f / 256.f);
    float var = sq * (1.f / 256.f) - mu * mu;
    float rs = rsqrtf(var + 1e-5f);
    float4 gg = reinterpret_cast<const float4*>(g)[lane];
    float4 bb = reinterpret_cast<const float4*>(be)[lane];
    ushort4 o;
    o.x = f2bf((v.x - mu) * rs * gg.x + bb.x);
    o.y = f2bf((v.y - mu) * rs * gg.y + bb.y);
    o.z = f2bf((v.z - mu) * rs * gg.z + bb.z);
    o.w = f2bf((v.w - mu) * rs * gg.w + bb.w);
    reinterpret_cast<ushort4*>(out + (size_t)row * 256)[lane] = o;
}

// ---------------- LayerNorm + linear + relu -> dur_pred (f32) ----------------
__global__ void ln_lin(const float* __restrict__ in, const float* __restrict__ g,
                       const float* __restrict__ be, const float* __restrict__ lw,
                       const float* __restrict__ lb, float* __restrict__ out) {
    int lane = threadIdx.x & 63;
    int wv = threadIdx.x >> 6;
    int row = blockIdx.x * 4 + wv;
    const float* p = in + (size_t)row * 256;
    float4 v = reinterpret_cast<const float4*>(p)[lane];
    float s = v.x + v.y + v.z + v.w;
    float sq = v.x * v.x + v.y * v.y + v.z * v.z + v.w * v.w;
    #pragma unroll
    for (int off = 32; off; off >>= 1) {
        s += __shfl_xor(s, off);
        sq += __shfl_xor(sq, off);
    }
    float mu = s * (1.f / 256.f);
    float var = sq * (1.f / 256.f) - mu * mu;
    float rs = rsqrtf(var + 1e-5f);
    float4 gg = reinterpret_cast<const float4*>(g)[lane];
    float4 bb = reinterpret_cast<const float4*>(be)[lane];
    float4 ww = reinterpret_cast<const float4*>(lw)[lane];
    float d = ((v.x - mu) * rs * gg.x + bb.x) * ww.x
            + ((v.y - mu) * rs * gg.y + bb.y) * ww.y
            + ((v.z - mu) * rs * gg.z + bb.z) * ww.z
            + ((v.w - mu) * rs * gg.w + bb.w) * ww.w;
    #pragma unroll
    for (int off = 32; off; off >>= 1) d += __shfl_xor(d, off);
    if (lane == 0) out[row] = fmaxf(d + lb[0], 0.f);
}

// ---------------- cumsum of durations ----------------
__global__ void cumsum_k(const int* __restrict__ tgt, int* __restrict__ cum, int T) {
    __shared__ int s[512];
    int b = blockIdx.x, tid = threadIdx.x;
    s[tid] = tgt[b * T + tid];
    __syncthreads();
    for (int off = 1; off < T; off <<= 1) {
        int v = (tid >= off) ? s[tid - off] : 0;
        __syncthreads();
        s[tid] += v;
        __syncthreads();
    }
    cum[b * T + tid] = s[tid];
}

// ---------------- length-regulate gather (exact fp32) ----------------
__global__ void lr_gather(const float* __restrict__ x, const int* __restrict__ cum,
                          float* __restrict__ out, int T, int M) {
    int b = blockIdx.y;
    int wv = threadIdx.x >> 6, lane = threadIdx.x & 63;
    int m = blockIdx.x * 4 + wv;
    if (m >= M) return;
    const int* c = cum + (size_t)b * T;
    int total = c[T - 1];
    float4 v = make_float4(0.f, 0.f, 0.f, 0.f);
    if (m < total) {
        int lo = 0, hi = T;
        while (lo < hi) {               // first idx with cum[idx] > m  (searchsorted right)
            int mid = (lo + hi) >> 1;
            if (c[mid] <= m) lo = mid + 1; else hi = mid;
        }
        int idx = lo < T ? lo : T - 1;
        v = *reinterpret_cast<const float4*>(x + ((size_t)(b * T + idx)) * 256 + lane * 4);
    }
    *reinterpret_cast<float4*>(out + ((size_t)b * M + m) * 256 + lane * 4) = v;
}

extern "C" void kernel_launch(void* const* d_in, const int* in_sizes, int n_in,
                              void* d_out, int out_size, void* d_ws, size_t ws_size,
                              hipStream_t stream) {
    const float* x   = (const float*)d_in[0];
    const float* w1  = (const float*)d_in[1];
    const float* b1  = (const float*)d_in[2];
    const float* g1  = (const float*)d_in[3];
    const float* be1 = (const float*)d_in[4];
    const float* w2  = (const float*)d_in[5];
    const float* b2  = (const float*)d_in[6];
    const float* g2  = (const float*)d_in[7];
    const float* be2 = (const float*)d_in[8];
    const float* lw  = (const float*)d_in[9];
    const float* lb  = (const float*)d_in[10];
    const int* tgt   = (const int*)d_in[11];
    float* out = (float*)d_out;

    const int B = 32, T = 512, C = 256;
    const int rows = B * T;                       // 16384
    const int M = (out_size - rows) / (B * C);    // 3584

    char* ws = (char*)d_ws;
    unsigned short* xb  = (unsigned short*)(ws);              //  8,388,608 B
    unsigned short* w1p = (unsigned short*)(ws + 8388608);    //    393,216 B
    unsigned short* w2p = (unsigned short*)(ws + 8781824);    //    393,216 B
    float* act          = (float*)(ws + 9175040);             // 16,777,216 B (a1, reused as a2)
    unsigned short* h1b = (unsigned short*)(ws + 25952256);   //  8,388,608 B
    int* cum            = (int*)(ws + 34340864);              //     65,536 B

    pack_x<<<(rows * C / 4 + 255) / 256, 256, 0, stream>>>(x, xb, rows * C / 4);
    pack_w<<<(C * C * 3 + 255) / 256, 256, 0, stream>>>(w1, w1p);
    pack_w<<<(C * C * 3 + 255) / 256, 256, 0, stream>>>(w2, w2p);

    conv_gemm<<<dim3(rows / BM, C / BN), 256, 0, stream>>>(xb, w1p, b1, act, T);
    ln_bf16<<<rows / 4, 256, 0, stream>>>(act, g1, be1, h1b);
    conv_gemm<<<dim3(rows / BM, C / BN), 256, 0, stream>>>(h1b, w2p, b2, act, T);
    ln_lin<<<rows / 4, 256, 0, stream>>>(act, g2, be2, lw, lb, out + (size_t)B * M * C);

    cumsum_k<<<B, 512, 0, stream>>>(tgt, cum, T);
    lr_gather<<<dim3((M + 3) / 4, B), 256, 0, stream>>>(x, cum, out, T, M);
}

// Round 2
// 82.131 us; speedup vs baseline: 1.4109x; 1.4109x over previous
//
#include <hip/hip_runtime.h>
#include <hip/hip_bf16.h>

typedef float f32x4 __attribute__((ext_vector_type(4)));
typedef __bf16 bf16x8 __attribute__((ext_vector_type(8)));

static __device__ __forceinline__ unsigned short f2bf(float f) {
    unsigned int u = __float_as_uint(f);
    unsigned int r = (u + 0x7fffu + ((u >> 16) & 1u)) >> 16;   // RNE
    return (unsigned short)r;
}

// ---------------- pack both weights: [F][Cin][3] f32 -> [F][kk*256+cin] bf16 ----------------
__global__ void pack_w2(const float* __restrict__ w1, const float* __restrict__ w2,
                        unsigned short* __restrict__ w1p, unsigned short* __restrict__ w2p) {
    int i = blockIdx.x * blockDim.x + threadIdx.x;
    const int n1 = 256 * 256 * 3;
    if (i >= 2 * n1) return;
    const float* w = (i < n1) ? w1 : w2;
    unsigned short* wp = (i < n1) ? w1p : w2p;
    int j = (i < n1) ? i : i - n1;
    int f = j / 768;
    int rem = j - f * 768;
    int cin = rem / 3;
    int kk = rem - cin * 3;
    wp[f * 768 + kk * 256 + cin] = f2bf(w[j]);
}

// ---------------------------------------------------------------------------
// Fused conv kernels. Tile: BM=64 output rows, BN=256 (all features), K=768.
// 512 threads = 8 waves, wave grid 2(M)x4(N); each wave 32x64 via 2x4 16x16x32 frags.
// LDS: As[66][256] bf16 (halo rows t-1..t+64), Bs[256][64] bf16 per K-step.
// Both XOR-swizzled: ushort idx ^= (row&7)<<3 to kill 16-way ds_read conflicts.
// ---------------------------------------------------------------------------
#define NKT 12

__global__ __launch_bounds__(512) void conv1_fused(
    const float* __restrict__ x, const unsigned short* __restrict__ Wp,
    const float* __restrict__ bias, const float* __restrict__ g,
    const float* __restrict__ be, unsigned short* __restrict__ h1b)
{
    __shared__ __align__(16) unsigned short smem[33280];   // As: [0,16896) Bs/Hs: [16896,33280)
    __shared__ float lnS[4][64], lnQ[4][64];
    unsigned short* As = smem;
    unsigned short* Bs = smem + 16896;

    const int tid = threadIdx.x;
    const int lane = tid & 63;
    const int w = tid >> 6;
    const int wmi = w >> 2, wni = w & 3;
    const int grp = lane >> 4, lr = lane & 15;

    const int blk = blockIdx.x;
    const int b = blk >> 3;
    const int t_base = (blk & 7) * 64;

    // ---- stage A: x rows t_base-1 .. t_base+64 (66 rows), f32 -> bf16, swizzled
    #pragma unroll
    for (int i = 0; i < 9; ++i) {
        int c = i * 512 + tid;
        if (c < 66 * 64) {
            int row = c >> 6, q = c & 63;
            int tt = t_base - 1 + row;
            ushort4 o = make_ushort4(0, 0, 0, 0);
            if ((unsigned)tt < 512u) {
                float4 v = *reinterpret_cast<const float4*>(x + ((size_t)(b * 512 + tt)) * 256 + q * 4);
                o.x = f2bf(v.x); o.y = f2bf(v.y); o.z = f2bf(v.z); o.w = f2bf(v.w);
            }
            *reinterpret_cast<ushort4*>(&As[row * 256 + ((q * 4) ^ ((row & 7) << 3))]) = o;
        }
    }

    f32x4 acc[2][4] = {};

    for (int kt = 0; kt < NKT; ++kt) {
        const int k0 = kt * 64;
        const int kk = kt >> 2;
        const int cin0 = (kt & 3) * 64;
        // stage Bs: Wp[n][k0..k0+63], 2048 uint4 chunks, swizzled dest
        #pragma unroll
        for (int i = 0; i < 4; ++i) {
            int c = i * 512 + tid;
            int row = c >> 3, seg = c & 7;
            uint4 v = *reinterpret_cast<const uint4*>(Wp + (size_t)row * 768 + k0 + seg * 8);
            *reinterpret_cast<uint4*>(&Bs[row * 64 + ((seg * 8) ^ ((row & 7) << 3))]) = v;
        }
        __syncthreads();
        #pragma unroll
        for (int ks = 0; ks < 2; ++ks) {
            bf16x8 af[2], bf[4];
            #pragma unroll
            for (int mi = 0; mi < 2; ++mi) {
                int tr = wmi * 32 + mi * 16 + lr + kk;
                int colu = cin0 + ks * 32 + grp * 8;
                af[mi] = *reinterpret_cast<const bf16x8*>(&As[tr * 256 + (colu ^ ((tr & 7) << 3))]);
            }
            #pragma unroll
            for (int ni = 0; ni < 4; ++ni) {
                int n = wni * 64 + ni * 16 + lr;
                bf[ni] = *reinterpret_cast<const bf16x8*>(&Bs[n * 64 + ((ks * 32 + grp * 8) ^ ((n & 7) << 3))]);
            }
            #pragma unroll
            for (int mi = 0; mi < 2; ++mi)
                #pragma unroll
                for (int ni = 0; ni < 4; ++ni)
                    acc[mi][ni] = __builtin_amdgcn_mfma_f32_16x16x32_bf16(af[mi], bf[ni], acc[mi][ni], 0, 0, 0);
        }
        __syncthreads();
    }

    // ---- epilogue: +bias, relu, LN over 256 features, bf16 out
    float bcol[4], gcol[4], becol[4];
    #pragma unroll
    for (int ni = 0; ni < 4; ++ni) {
        int col = wni * 64 + ni * 16 + lr;
        bcol[ni] = bias[col]; gcol[ni] = g[col]; becol[ni] = be[col];
    }
    float vv[2][4][4];
    #pragma unroll
    for (int mi = 0; mi < 2; ++mi)
        #pragma unroll
        for (int ni = 0; ni < 4; ++ni)
            #pragma unroll
            for (int r = 0; r < 4; ++r)
                vv[mi][ni][r] = fmaxf(acc[mi][ni][r] + bcol[ni], 0.f);

    #pragma unroll
    for (int mi = 0; mi < 2; ++mi)
        #pragma unroll
        for (int r = 0; r < 4; ++r) {
            float s = vv[mi][0][r] + vv[mi][1][r] + vv[mi][2][r] + vv[mi][3][r];
            float q = vv[mi][0][r] * vv[mi][0][r] + vv[mi][1][r] * vv[mi][1][r]
                    + vv[mi][2][r] * vv[mi][2][r] + vv[mi][3][r] * vv[mi][3][r];
            #pragma unroll
            for (int off = 1; off < 16; off <<= 1) {
                s += __shfl_xor(s, off);
                q += __shfl_xor(q, off);
            }
            if (lr == 0) {
                int R = wmi * 32 + mi * 16 + grp * 4 + r;
                lnS[wni][R] = s; lnQ[wni][R] = q;
            }
        }
    __syncthreads();

    unsigned short* Hs = Bs;   // reuse
    #pragma unroll
    for (int mi = 0; mi < 2; ++mi)
        #pragma unroll
        for (int r = 0; r < 4; ++r) {
            int R = wmi * 32 + mi * 16 + grp * 4 + r;
            float mu = (lnS[0][R] + lnS[1][R] + lnS[2][R] + lnS[3][R]) * (1.f / 256.f);
            float var = (lnQ[0][R] + lnQ[1][R] + lnQ[2][R] + lnQ[3][R]) * (1.f / 256.f) - mu * mu;
            float rs = rsqrtf(var + 1e-5f);
            #pragma unroll
            for (int ni = 0; ni < 4; ++ni) {
                int col = wni * 64 + ni * 16 + lr;
                float h = (vv[mi][ni][r] - mu) * rs * gcol[ni] + becol[ni];
                Hs[R * 256 + (col ^ ((R & 7) << 3))] = f2bf(h);
            }
        }
    __syncthreads();
    // vectorized global write of the 64x256 bf16 tile
    #pragma unroll
    for (int i = 0; i < 4; ++i) {
        int c = i * 512 + tid;          // 2048 chunks of 16B
        int row = c >> 5, seg = c & 31;
        uint4 v = *reinterpret_cast<const uint4*>(&Hs[row * 256 + ((seg * 8) ^ ((row & 7) << 3))]);
        *reinterpret_cast<uint4*>(h1b + ((size_t)(b * 512 + t_base + row)) * 256 + seg * 8) = v;
    }
}

__global__ __launch_bounds__(512) void conv2_fused(
    const unsigned short* __restrict__ h1b, const unsigned short* __restrict__ Wp,
    const float* __restrict__ bias, const float* __restrict__ g,
    const float* __restrict__ be, const float* __restrict__ lw,
    const float* __restrict__ lb, float* __restrict__ dur)
{
    __shared__ __align__(16) unsigned short smem[33280];
    __shared__ float lnS[4][64], lnQ[4][64], lnD[4][64];
    unsigned short* As = smem;
    unsigned short* Bs = smem + 16896;

    const int tid = threadIdx.x;
    const int lane = tid & 63;
    const int w = tid >> 6;
    const int wmi = w >> 2, wni = w & 3;
    const int grp = lane >> 4, lr = lane & 15;

    const int blk = blockIdx.x;
    const int b = blk >> 3;
    const int t_base = (blk & 7) * 64;

    // ---- stage A: h1b rows t_base-1 .. t_base+64 (66 rows), bf16, swizzled
    #pragma unroll
    for (int i = 0; i < 5; ++i) {
        int c = i * 512 + tid;
        if (c < 66 * 32) {
            int row = c >> 5, seg = c & 31;
            int tt = t_base - 1 + row;
            uint4 v = make_uint4(0u, 0u, 0u, 0u);
            if ((unsigned)tt < 512u)
                v = *reinterpret_cast<const uint4*>(h1b + ((size_t)(b * 512 + tt)) * 256 + seg * 8);
            *reinterpret_cast<uint4*>(&As[row * 256 + ((seg * 8) ^ ((row & 7) << 3))]) = v;
        }
    }

    f32x4 acc[2][4] = {};

    for (int kt = 0; kt < NKT; ++kt) {
        const int k0 = kt * 64;
        const int kk = kt >> 2;
        const int cin0 = (kt & 3) * 64;
        #pragma unroll
        for (int i = 0; i < 4; ++i) {
            int c = i * 512 + tid;
            int row = c >> 3, seg = c & 7;
            uint4 v = *reinterpret_cast<const uint4*>(Wp + (size_t)row * 768 + k0 + seg * 8);
            *reinterpret_cast<uint4*>(&Bs[row * 64 + ((seg * 8) ^ ((row & 7) << 3))]) = v;
        }
        __syncthreads();
        #pragma unroll
        for (int ks = 0; ks < 2; ++ks) {
            bf16x8 af[2], bf[4];
            #pragma unroll
            for (int mi = 0; mi < 2; ++mi) {
                int tr = wmi * 32 + mi * 16 + lr + kk;
                int colu = cin0 + ks * 32 + grp * 8;
                af[mi] = *reinterpret_cast<const bf16x8*>(&As[tr * 256 + (colu ^ ((tr & 7) << 3))]);
            }
            #pragma unroll
            for (int ni = 0; ni < 4; ++ni) {
                int n = wni * 64 + ni * 16 + lr;
                bf[ni] = *reinterpret_cast<const bf16x8*>(&Bs[n * 64 + ((ks * 32 + grp * 8) ^ ((n & 7) << 3))]);
            }
            #pragma unroll
            for (int mi = 0; mi < 2; ++mi)
                #pragma unroll
                for (int ni = 0; ni < 4; ++ni)
                    acc[mi][ni] = __builtin_amdgcn_mfma_f32_16x16x32_bf16(af[mi], bf[ni], acc[mi][ni], 0, 0, 0);
        }
        __syncthreads();
    }

    // ---- epilogue: +bias, relu, LN, dot with lin_w, relu -> dur[64]
    float bcol[4], gcol[4], becol[4], wcol[4];
    #pragma unroll
    for (int ni = 0; ni < 4; ++ni) {
        int col = wni * 64 + ni * 16 + lr;
        bcol[ni] = bias[col]; gcol[ni] = g[col]; becol[ni] = be[col]; wcol[ni] = lw[col];
    }
    float vv[2][4][4];
    #pragma unroll
    for (int mi = 0; mi < 2; ++mi)
        #pragma unroll
        for (int ni = 0; ni < 4; ++ni)
            #pragma unroll
            for (int r = 0; r < 4; ++r)
                vv[mi][ni][r] = fmaxf(acc[mi][ni][r] + bcol[ni], 0.f);

    #pragma unroll
    for (int mi = 0; mi < 2; ++mi)
        #pragma unroll
        for (int r = 0; r < 4; ++r) {
            float s = vv[mi][0][r] + vv[mi][1][r] + vv[mi][2][r] + vv[mi][3][r];
            float q = vv[mi][0][r] * vv[mi][0][r] + vv[mi][1][r] * vv[mi][1][r]
                    + vv[mi][2][r] * vv[mi][2][r] + vv[mi][3][r] * vv[mi][3][r];
            #pragma unroll
            for (int off = 1; off < 16; off <<= 1) {
                s += __shfl_xor(s, off);
                q += __shfl_xor(q, off);
            }
            if (lr == 0) {
                int R = wmi * 32 + mi * 16 + grp * 4 + r;
                lnS[wni][R] = s; lnQ[wni][R] = q;
            }
        }
    __syncthreads();
    #pragma unroll
    for (int mi = 0; mi < 2; ++mi)
        #pragma unroll
        for (int r = 0; r < 4; ++r) {
            int R = wmi * 32 + mi * 16 + grp * 4 + r;
            float mu = (lnS[0][R] + lnS[1][R] + lnS[2][R] + lnS[3][R]) * (1.f / 256.f);
            float var = (lnQ[0][R] + lnQ[1][R] + lnQ[2][R] + lnQ[3][R]) * (1.f / 256.f) - mu * mu;
            float rs = rsqrtf(var + 1e-5f);
            float d = ((vv[mi][0][r] - mu) * rs * gcol[0] + becol[0]) * wcol[0]
                    + ((vv[mi][1][r] - mu) * rs * gcol[1] + becol[1]) * wcol[1]
                    + ((vv[mi][2][r] - mu) * rs * gcol[2] + becol[2]) * wcol[2]
                    + ((vv[mi][3][r] - mu) * rs * gcol[3] + becol[3]) * wcol[3];
            #pragma unroll
            for (int off = 1; off < 16; off <<= 1) d += __shfl_xor(d, off);
            if (lr == 0) lnD[wni][R] = d;
        }
    __syncthreads();
    if (tid < 64) {
        float dd = lnD[0][tid] + lnD[1][tid] + lnD[2][tid] + lnD[3][tid] + lb[0];
        dur[(size_t)b * 512 + t_base + tid] = fmaxf(dd, 0.f);
    }
}

// ---------------- cumsum of durations ----------------
__global__ void cumsum_k(const int* __restrict__ tgt, int* __restrict__ cum, int T) {
    __shared__ int s[512];
    int b = blockIdx.x, tid = threadIdx.x;
    s[tid] = tgt[b * T + tid];
    __syncthreads();
    for (int off = 1; off < T; off <<= 1) {
        int v = (tid >= off) ? s[tid - off] : 0;
        __syncthreads();
        s[tid] += v;
        __syncthreads();
    }
    cum[b * T + tid] = s[tid];
}

// ---------------- length-regulate gather (exact fp32) ----------------
__global__ void lr_gather(const float* __restrict__ x, const int* __restrict__ cum,
                          float* __restrict__ out, int T, int M) {
    int b = blockIdx.y;
    int wv = threadIdx.x >> 6, lane = threadIdx.x & 63;
    int m = blockIdx.x * 4 + wv;
    if (m >= M) return;
    const int* c = cum + (size_t)b * T;
    int total = c[T - 1];
    float4 v = make_float4(0.f, 0.f, 0.f, 0.f);
    if (m < total) {
        int lo = 0, hi = T;
        while (lo < hi) {               // first idx with cum[idx] > m  (searchsorted right)
            int mid = (lo + hi) >> 1;
            if (c[mid] <= m) lo = mid + 1; else hi = mid;
        }
        int idx = lo < T ? lo : T - 1;
        v = *reinterpret_cast<const float4*>(x + ((size_t)(b * T + idx)) * 256 + lane * 4);
    }
    *reinterpret_cast<float4*>(out + ((size_t)b * M + m) * 256 + lane * 4) = v;
}

extern "C" void kernel_launch(void* const* d_in, const int* in_sizes, int n_in,
                              void* d_out, int out_size, void* d_ws, size_t ws_size,
                              hipStream_t stream) {
    const float* x   = (const float*)d_in[0];
    const float* w1  = (const float*)d_in[1];
    const float* b1  = (const float*)d_in[2];
    const float* g1  = (const float*)d_in[3];
    const float* be1 = (const float*)d_in[4];
    const float* w2  = (const float*)d_in[5];
    const float* b2  = (const float*)d_in[6];
    const float* g2  = (const float*)d_in[7];
    const float* be2 = (const float*)d_in[8];
    const float* lw  = (const float*)d_in[9];
    const float* lb  = (const float*)d_in[10];
    const int* tgt   = (const int*)d_in[11];
    float* out = (float*)d_out;

    const int B = 32, T = 512, C = 256;
    const int rows = B * T;                       // 16384
    const int M = (out_size - rows) / (B * C);    // 3584

    char* ws = (char*)d_ws;
    unsigned short* w1p = (unsigned short*)(ws);              //   393,216 B
    unsigned short* w2p = (unsigned short*)(ws + 393216);     //   393,216 B
    unsigned short* h1b = (unsigned short*)(ws + 786432);     // 8,388,608 B
    int* cum            = (int*)(ws + 9175040);               //    65,536 B

    pack_w2<<<(2 * C * C * 3 + 255) / 256, 256, 0, stream>>>(w1, w2, w1p, w2p);

    conv1_fused<<<rows / 64, 512, 0, stream>>>(x, w1p, b1, g1, be1, h1b);
    conv2_fused<<<rows / 64, 512, 0, stream>>>(h1b, w2p, b2, g2, be2, lw, lb,
                                               out + (size_t)B * M * C);

    cumsum_k<<<B, 512, 0, stream>>>(tgt, cum, T);
    lr_gather<<<dim3((M + 3) / 4, B), 256, 0, stream>>>(x, cum, out, T, M);
}

// Round 3
// 79.124 us; speedup vs baseline: 1.4646x; 1.0380x over previous
//
#include <hip/hip_runtime.h>
#include <hip/hip_bf16.h>

typedef float f32x4 __attribute__((ext_vector_type(4)));
typedef __bf16 bf16x8 __attribute__((ext_vector_type(8)));

static __device__ __forceinline__ unsigned short f2bf(float f) {
    unsigned int u = __float_as_uint(f);
    unsigned int r = (u + 0x7fffu + ((u >> 16) & 1u)) >> 16;   // RNE
    return (unsigned short)r;
}

// async global->LDS, 16B per lane; LDS dest = wave-uniform base + lane*16
static __device__ __forceinline__ void gll16(const void* g, void* l) {
    __builtin_amdgcn_global_load_lds(
        (const __attribute__((address_space(1))) unsigned int*)g,
        (__attribute__((address_space(3))) unsigned int*)l, 16, 0, 0);
}

// ---------------------------------------------------------------------------
// prep: pack both conv weights into tile-major MFMA-ready layout + cumsum.
// Wp layout: for kt(24 tiles of K=32), nb(16 row-blocks), l(64 lanes):
//   chunk at ushort off (kt*1024 + nb*64 + l)*8 + e holds
//   W[row = nb*16 + (l&15)][k = kt*32 + (l>>4)*8 + e]   (k -> tap kt>>3, cin (kt&7)*32+..)
// so a linear global_load_lds gives conflict-free linear frag reads.
// ---------------------------------------------------------------------------
__global__ __launch_bounds__(512) void prep(
    const float* __restrict__ w1, const float* __restrict__ w2,
    unsigned short* __restrict__ w1p, unsigned short* __restrict__ w2p,
    const int* __restrict__ tgt, int* __restrict__ cum)
{
    int blk = blockIdx.x;
    if (blk < 768) {
        int gi = blk * 512 + threadIdx.x;            // 0..393215
        const float* w = (gi < 196608) ? w1 : w2;
        unsigned short* wp = (gi < 196608) ? w1p : w2p;
        int j = (gi < 196608) ? gi : gi - 196608;    // 0..196607
        int e = j & 7;
        int ch = j >> 3;                             // 0..24575
        int kt = ch >> 10;                           // 0..23
        int rem = ch & 1023;
        int nb = rem >> 6, l = rem & 63;
        int n = nb * 16 + (l & 15);
        int cin = (kt & 7) * 32 + (l >> 4) * 8 + e;
        int kk = kt >> 3;
        wp[j] = f2bf(w[n * 768 + cin * 3 + kk]);
    } else {
        __shared__ int s[512];
        int b = blk - 768, tid = threadIdx.x;
        s[tid] = tgt[b * 512 + tid];
        __syncthreads();
        for (int off = 1; off < 512; off <<= 1) {
            int v = (tid >= off) ? s[tid - off] : 0;
            __syncthreads();
            s[tid] += v;
            __syncthreads();
        }
        cum[b * 512 + tid] = s[tid];
    }
}

// ---------------------------------------------------------------------------
// gather part (shared by both hetero kernels): 32 mel rows / block, 8 waves
// ---------------------------------------------------------------------------
static __device__ __forceinline__ void gather_part(
    int gblk, int phase, const float* __restrict__ x, const int* __restrict__ cum,
    float* __restrict__ out, int M, int wv, int lane)
{
    int b = gblk / 56;
    int r0 = (gblk % 56) * 32 + phase;
    const int* c = cum + b * 512;
    int total = c[511];
    #pragma unroll
    for (int i = 0; i < 4; ++i) {
        int m = r0 + i * 8 + wv;
        float4 v = make_float4(0.f, 0.f, 0.f, 0.f);
        if (m < total) {
            int lo = 0, hi = 512;
            while (lo < hi) { int mid = (lo + hi) >> 1; if (c[mid] <= m) lo = mid + 1; else hi = mid; }
            int idx = lo < 512 ? lo : 511;
            v = *reinterpret_cast<const float4*>(x + ((size_t)(b * 512 + idx)) * 256 + lane * 4);
        }
        *reinterpret_cast<float4*>(out + ((size_t)b * M + m) * 256 + lane * 4) = v;
    }
}

// ---------------------------------------------------------------------------
// conv1 + gather(first half). BM=64, BN=256, BK=32 (24 tiles), 8 waves 2Mx4N.
// ---------------------------------------------------------------------------
__global__ __launch_bounds__(512, 4) void conv1_hetero(
    const float* __restrict__ x, const unsigned short* __restrict__ Wp,
    const float* __restrict__ bias, const float* __restrict__ g,
    const float* __restrict__ be, unsigned short* __restrict__ h1b,
    const int* __restrict__ cum, float* __restrict__ out, int M)
{
    __shared__ __align__(16) unsigned short As[66 * 256];
    __shared__ __align__(16) unsigned short Bsm[2][8192];
    __shared__ float lnS[4][64], lnQ[4][64];

    const int tid = threadIdx.x;
    const int lane = tid & 63;
    const int wv = tid >> 6;

    if (blockIdx.x >= 256) {
        gather_part(blockIdx.x - 256, 0, x, cum, out, M, wv, lane);
        return;
    }

    const int wmi = wv >> 2, wni = wv & 3;
    const int grp = lane >> 4, lr = lane & 15;
    const int b = blockIdx.x >> 3;
    const int t_base = (blockIdx.x & 7) * 64;

    // ---- A stage: x rows t_base-1 .. t_base+64 -> bf16, XOR-swizzled (row&7)<<3
    #pragma unroll
    for (int i = 0; i < 9; ++i) {
        int cc = i * 512 + tid;
        if (cc < 66 * 64) {
            int row = cc >> 6, q = cc & 63;
            int tt = t_base - 1 + row;
            ushort4 o = make_ushort4(0, 0, 0, 0);
            if ((unsigned)tt < 512u) {
                float4 v = *reinterpret_cast<const float4*>(x + ((size_t)(b * 512 + tt)) * 256 + q * 4);
                o.x = f2bf(v.x); o.y = f2bf(v.y); o.z = f2bf(v.z); o.w = f2bf(v.w);
            }
            *reinterpret_cast<ushort4*>(&As[row * 256 + ((q * 4) ^ ((row & 7) << 3))]) = o;
        }
    }

    // ---- B double-buffered pipeline via global_load_lds
    const char* wpB = (const char*)Wp;
    char* bs0 = (char*)&Bsm[0][0];
    #define STAGE_B(kt, buf) do {                                              \
        const char* _s = wpB + (kt) * 16384 + wv * 2048 + lane * 16;           \
        char* _d = bs0 + (buf) * 16384 + wv * 2048;                            \
        gll16(_s, _d); gll16(_s + 1024, _d + 1024);                            \
    } while (0)

    STAGE_B(0, 0);
    __syncthreads();

    f32x4 acc[2][4] = {};
    int cur = 0;
    for (int kt = 0; kt < 24; ++kt) {
        if (kt < 23) STAGE_B(kt + 1, cur ^ 1);
        const int kk = kt >> 3, cin0 = (kt & 7) * 32;
        bf16x8 af[2], bfr[4];
        #pragma unroll
        for (int mi = 0; mi < 2; ++mi) {
            int tr = wmi * 32 + mi * 16 + lr + kk;
            af[mi] = *reinterpret_cast<const bf16x8*>(&As[tr * 256 + ((cin0 + grp * 8) ^ ((tr & 7) << 3))]);
        }
        #pragma unroll
        for (int ni = 0; ni < 4; ++ni)
            bfr[ni] = *reinterpret_cast<const bf16x8*>(&Bsm[cur][(wni * 4 + ni) * 512 + lane * 8]);
        #pragma unroll
        for (int mi = 0; mi < 2; ++mi)
            #pragma unroll
            for (int ni = 0; ni < 4; ++ni)
                acc[mi][ni] = __builtin_amdgcn_mfma_f32_16x16x32_bf16(af[mi], bfr[ni], acc[mi][ni], 0, 0, 0);
        __syncthreads();
        cur ^= 1;
    }

    // ---- epilogue: bias+relu (in place), LN, direct pre-swizzled bf16 store
    float bcol[4], gcol[4], becol[4];
    #pragma unroll
    for (int ni = 0; ni < 4; ++ni) {
        int col = wni * 64 + ni * 16 + lr;
        bcol[ni] = bias[col]; gcol[ni] = g[col]; becol[ni] = be[col];
    }
    #pragma unroll
    for (int mi = 0; mi < 2; ++mi)
        #pragma unroll
        for (int ni = 0; ni < 4; ++ni)
            #pragma unroll
            for (int r = 0; r < 4; ++r)
                acc[mi][ni][r] = fmaxf(acc[mi][ni][r] + bcol[ni], 0.f);

    #pragma unroll
    for (int mi = 0; mi < 2; ++mi)
        #pragma unroll
        for (int r = 0; r < 4; ++r) {
            float s = acc[mi][0][r] + acc[mi][1][r] + acc[mi][2][r] + acc[mi][3][r];
            float q = acc[mi][0][r] * acc[mi][0][r] + acc[mi][1][r] * acc[mi][1][r]
                    + acc[mi][2][r] * acc[mi][2][r] + acc[mi][3][r] * acc[mi][3][r];
            #pragma unroll
            for (int off = 1; off < 16; off <<= 1) {
                s += __shfl_xor(s, off);
                q += __shfl_xor(q, off);
            }
            if (lr == 0) {
                int R = wmi * 32 + mi * 16 + grp * 4 + r;
                lnS[wni][R] = s; lnQ[wni][R] = q;
            }
        }
    __syncthreads();
    #pragma unroll
    for (int mi = 0; mi < 2; ++mi)
        #pragma unroll
        for (int r = 0; r < 4; ++r) {
            int R = wmi * 32 + mi * 16 + grp * 4 + r;
            float mu = (lnS[0][R] + lnS[1][R] + lnS[2][R] + lnS[3][R]) * (1.f / 256.f);
            float var = (lnQ[0][R] + lnQ[1][R] + lnQ[2][R] + lnQ[3][R]) * (1.f / 256.f) - mu * mu;
            float rs = rsqrtf(var + 1e-5f);
            size_t rowoff = ((size_t)(b * 512 + t_base + R)) * 256;
            #pragma unroll
            for (int ni = 0; ni < 4; ++ni) {
                int col = wni * 64 + ni * 16 + lr;
                float h = (acc[mi][ni][r] - mu) * rs * gcol[ni] + becol[ni];
                h1b[rowoff + (col ^ ((R & 7) << 3))] = f2bf(h);   // pre-swizzled for conv2
            }
        }
    #undef STAGE_B
}

// ---------------------------------------------------------------------------
// conv2 + LN + linear + relu -> dur, + gather(second half)
// ---------------------------------------------------------------------------
__global__ __launch_bounds__(512, 4) void conv2_hetero(
    const unsigned short* __restrict__ h1b, const unsigned short* __restrict__ Wp,
    const float* __restrict__ bias, const float* __restrict__ g,
    const float* __restrict__ be, const float* __restrict__ lw,
    const float* __restrict__ lb, float* __restrict__ dur,
    const int* __restrict__ cum, const float* __restrict__ x,
    float* __restrict__ out, int M)
{
    __shared__ __align__(16) unsigned short As[66 * 256];
    __shared__ __align__(16) unsigned short Bsm[2][8192];
    __shared__ float lnS[4][64], lnQ[4][64], lnD[4][64];

    const int tid = threadIdx.x;
    const int lane = tid & 63;
    const int wv = tid >> 6;

    if (blockIdx.x >= 256) {
        gather_part(blockIdx.x - 256, 1792, x, cum, out, M, wv, lane);
        return;
    }

    const int wmi = wv >> 2, wni = wv & 3;
    const int grp = lane >> 4, lr = lane & 15;
    const int b = blockIdx.x >> 3;
    const int t_base = (blockIdx.x & 7) * 64;

    // ---- A stage: interior rows 1..64 via global_load_lds (h1b is pre-swizzled)
    {
        const char* src = (const char*)h1b + ((size_t)(b * 512 + t_base)) * 512 + wv * 4096 + lane * 16;
        char* dst = (char*)&As[256] + wv * 4096;
        #pragma unroll
        for (int i = 0; i < 4; ++i) gll16(src + i * 1024, dst + i * 1024);
    }
    // halo rows 0 (t_base-1) and 65 (t_base+64), zero-padded
    if (tid < 32) {
        int tt = t_base - 1;
        uint4 v = make_uint4(0u, 0u, 0u, 0u);
        if (tt >= 0)
            v = *reinterpret_cast<const uint4*>((const char*)h1b + ((size_t)(b * 512 + tt)) * 512 + tid * 16);
        *reinterpret_cast<uint4*>((char*)As + tid * 16) = v;
    } else if (tid < 64) {
        int t2 = tid - 32, tt = t_base + 64;
        uint4 v = make_uint4(0u, 0u, 0u, 0u);
        if (tt < 512)
            v = *reinterpret_cast<const uint4*>((const char*)h1b + ((size_t)(b * 512 + tt)) * 512 + t2 * 16);
        *reinterpret_cast<uint4*>((char*)&As[65 * 256] + t2 * 16) = v;
    }

    const char* wpB = (const char*)Wp;
    char* bs0 = (char*)&Bsm[0][0];
    #define STAGE_B(kt, buf) do {                                              \
        const char* _s = wpB + (kt) * 16384 + wv * 2048 + lane * 16;           \
        char* _d = bs0 + (buf) * 16384 + wv * 2048;                            \
        gll16(_s, _d); gll16(_s + 1024, _d + 1024);                            \
    } while (0)

    STAGE_B(0, 0);
    __syncthreads();

    f32x4 acc[2][4] = {};
    int cur = 0;
    for (int kt = 0; kt < 24; ++kt) {
        if (kt < 23) STAGE_B(kt + 1, cur ^ 1);
        const int kk = kt >> 3, cin0 = (kt & 7) * 32;
        bf16x8 af[2], bfr[4];
        #pragma unroll
        for (int mi = 0; mi < 2; ++mi) {
            int tr = wmi * 32 + mi * 16 + lr + kk;
            // h1b swizzle follows absolute t = t_base + tr - 1 -> bits (tr+7)&7
            af[mi] = *reinterpret_cast<const bf16x8*>(&As[tr * 256 + ((cin0 + grp * 8) ^ (((tr + 7) & 7) << 3))]);
        }
        #pragma unroll
        for (int ni = 0; ni < 4; ++ni)
            bfr[ni] = *reinterpret_cast<const bf16x8*>(&Bsm[cur][(wni * 4 + ni) * 512 + lane * 8]);
        #pragma unroll
        for (int mi = 0; mi < 2; ++mi)
            #pragma unroll
            for (int ni = 0; ni < 4; ++ni)
                acc[mi][ni] = __builtin_amdgcn_mfma_f32_16x16x32_bf16(af[mi], bfr[ni], acc[mi][ni], 0, 0, 0);
        __syncthreads();
        cur ^= 1;
    }

    // ---- epilogue: bias+relu, LN, dot lin_w, relu -> dur[64]
    float bcol[4], gcol[4], becol[4], wcol[4];
    #pragma unroll
    for (int ni = 0; ni < 4; ++ni) {
        int col = wni * 64 + ni * 16 + lr;
        bcol[ni] = bias[col]; gcol[ni] = g[col]; becol[ni] = be[col]; wcol[ni] = lw[col];
    }
    #pragma unroll
    for (int mi = 0; mi < 2; ++mi)
        #pragma unroll
        for (int ni = 0; ni < 4; ++ni)
            #pragma unroll
            for (int r = 0; r < 4; ++r)
                acc[mi][ni][r] = fmaxf(acc[mi][ni][r] + bcol[ni], 0.f);

    #pragma unroll
    for (int mi = 0; mi < 2; ++mi)
        #pragma unroll
        for (int r = 0; r < 4; ++r) {
            float s = acc[mi][0][r] + acc[mi][1][r] + acc[mi][2][r] + acc[mi][3][r];
            float q = acc[mi][0][r] * acc[mi][0][r] + acc[mi][1][r] * acc[mi][1][r]
                    + acc[mi][2][r] * acc[mi][2][r] + acc[mi][3][r] * acc[mi][3][r];
            #pragma unroll
            for (int off = 1; off < 16; off <<= 1) {
                s += __shfl_xor(s, off);
                q += __shfl_xor(q, off);
            }
            if (lr == 0) {
                int R = wmi * 32 + mi * 16 + grp * 4 + r;
                lnS[wni][R] = s; lnQ[wni][R] = q;
            }
        }
    __syncthreads();
    #pragma unroll
    for (int mi = 0; mi < 2; ++mi)
        #pragma unroll
        for (int r = 0; r < 4; ++r) {
            int R = wmi * 32 + mi * 16 + grp * 4 + r;
            float mu = (lnS[0][R] + lnS[1][R] + lnS[2][R] + lnS[3][R]) * (1.f / 256.f);
            float var = (lnQ[0][R] + lnQ[1][R] + lnQ[2][R] + lnQ[3][R]) * (1.f / 256.f) - mu * mu;
            float rs = rsqrtf(var + 1e-5f);
            float d = ((acc[mi][0][r] - mu) * rs * gcol[0] + becol[0]) * wcol[0]
                    + ((acc[mi][1][r] - mu) * rs * gcol[1] + becol[1]) * wcol[1]
                    + ((acc[mi][2][r] - mu) * rs * gcol[2] + becol[2]) * wcol[2]
                    + ((acc[mi][3][r] - mu) * rs * gcol[3] + becol[3]) * wcol[3];
            #pragma unroll
            for (int off = 1; off < 16; off <<= 1) d += __shfl_xor(d, off);
            if (lr == 0) lnD[wni][R] = d;
        }
    __syncthreads();
    if (tid < 64) {
        float dd = lnD[0][tid] + lnD[1][tid] + lnD[2][tid] + lnD[3][tid] + lb[0];
        dur[(size_t)b * 512 + t_base + tid] = fmaxf(dd, 0.f);
    }
    #undef STAGE_B
}

extern "C" void kernel_launch(void* const* d_in, const int* in_sizes, int n_in,
                              void* d_out, int out_size, void* d_ws, size_t ws_size,
                              hipStream_t stream) {
    const float* x   = (const float*)d_in[0];
    const float* w1  = (const float*)d_in[1];
    const float* b1  = (const float*)d_in[2];
    const float* g1  = (const float*)d_in[3];
    const float* be1 = (const float*)d_in[4];
    const float* w2  = (const float*)d_in[5];
    const float* b2  = (const float*)d_in[6];
    const float* g2  = (const float*)d_in[7];
    const float* be2 = (const float*)d_in[8];
    const float* lw  = (const float*)d_in[9];
    const float* lb  = (const float*)d_in[10];
    const int* tgt   = (const int*)d_in[11];
    float* out = (float*)d_out;

    const int B = 32, T = 512, C = 256;
    const int rows = B * T;                       // 16384
    const int M = (out_size - rows) / (B * C);    // 3584

    char* ws = (char*)d_ws;
    unsigned short* w1p = (unsigned short*)(ws);              //   393,216 B
    unsigned short* w2p = (unsigned short*)(ws + 393216);     //   393,216 B
    unsigned short* h1b = (unsigned short*)(ws + 786432);     // 8,388,608 B
    int* cum            = (int*)(ws + 9175040);               //    65,536 B

    prep<<<800, 512, 0, stream>>>(w1, w2, w1p, w2p, tgt, cum);
    // grid = 256 conv blocks + 32 batches * 56 gather blocks = 2048
    conv1_hetero<<<2048, 512, 0, stream>>>(x, w1p, b1, g1, be1, h1b, cum, out, M);
    conv2_hetero<<<2048, 512, 0, stream>>>(h1b, w2p, b2, g2, be2, lw, lb,
                                           out + (size_t)B * M * C, cum, x, out, M);
}